// Round 8
// baseline (160.040 us; speedup 1.0000x reference)
//
#include <hip/hip_runtime.h>
#include <hip/hip_bf16.h>
#include <cstdint>

#define B_    2
#define C_    256
#define H_    64
#define W_    64
#define P_    (H_*W_)      // 4096
#define N_    4
#define RAD   4
#define K2_   81
#define CTOT  (4*K2_)      // 324

typedef __bf16 bf16x8 __attribute__((ext_vector_type(8)));
typedef float  f32x4  __attribute__((ext_vector_type(4)));

// ---------------------------------------------------------------------------
// Transpose + convert, both maps in one dispatch:
// in (B, C, P) fp32  ->  out (B, P, C) bf16
// ---------------------------------------------------------------------------
__global__ void transpose_cvt(const float* __restrict__ in0,
                              const float* __restrict__ in1,
                              __hip_bfloat16* __restrict__ out0,
                              __hip_bfloat16* __restrict__ out1) {
    __shared__ float tile[32][33];
    const int z     = blockIdx.z;
    const int which = z >> 1;
    const int b     = z & 1;
    const float* in          = which ? in1  : in0;
    __hip_bfloat16* out      = which ? out1 : out0;
    const int p0 = blockIdx.x * 32;
    const int c0 = blockIdx.y * 32;
    const int tx = threadIdx.x;   // 0..31
    const int ty = threadIdx.y;   // 0..7
    const float* src = in + ((size_t)b * C_ + c0) * P_ + p0;
    #pragma unroll
    for (int i = 0; i < 32; i += 8)
        tile[ty + i][tx] = src[(size_t)(ty + i) * P_ + tx];   // tile[c][p]
    __syncthreads();
    __hip_bfloat16* dst = out + ((size_t)b * P_ + p0) * C_ + c0;
    #pragma unroll
    for (int i = 0; i < 32; i += 8)
        dst[(size_t)(ty + i) * C_ + tx] = __float2bfloat16(tile[tx][ty + i]);
}

// ---------------------------------------------------------------------------
// Batched GEMM, BARRIER-FREE K-loop: operand fragments loaded DIRECTLY from
// global memory (each 16x16x32 A/B fragment = one contiguous 16B dwordx4 per
// lane; rows are 512B-aligned). No LDS staging, no vmcnt(0)+barrier drains —
// the whole 8-segment K-loop is one flat unrolled block the compiler can
// software-pipeline freely. Operand tile rows are read by 2 waves each
// (wave-row/col pairs on the same CU) -> L1/L2 absorbs the redundancy;
// B-slabs stay L2-resident under the default x-fastest 2D dispatch (R6
// lesson: do NOT remap blocks to XCDs).
// Accumulation order identical to the staged version -> bitwise-same output.
// LDS used only for the epilogue tile (vectorized c0 store + fused pool1).
// ---------------------------------------------------------------------------
#define TSTR 136   // epilogue tile stride in shorts (272 B -> 16B-aligned)

__global__ __launch_bounds__(256) void gemm_corr(
    const short* __restrict__ f1t,   // (B, 4096, 256) bf16 bits
    const short* __restrict__ f2t,   // (B, 4096, 256) bf16 bits
    __hip_bfloat16* __restrict__ corr0,  // (B, 4096, 64, 64) bf16
    __hip_bfloat16* __restrict__ corr1)  // (B, 4096, 32, 32) bf16
{
    __shared__ short smem[128 * TSTR];   // 34,816 B epilogue tile only

    const int tid  = threadIdx.x;
    const int lane = tid & 63;
    const int wv   = tid >> 6;
    const int wm   = (wv >> 1) * 64;
    const int wn   = (wv & 1) * 64;
    const int b    = blockIdx.z;
    const int bx   = blockIdx.x;
    const int m0   = blockIdx.y * 128;
    const int n0   = bx * 128;
    const int qd   = lane >> 4;
    const int l15  = lane & 15;

    // per-fragment global base pointers (k-offset advances by immediates)
    const short* aB[4];
    const short* bB[4];
    #pragma unroll
    for (int i = 0; i < 4; ++i) {
        aB[i] = f1t + ((size_t)(b * P_ + m0 + wm + i * 16 + l15)) * C_ + qd * 8;
        bB[i] = f2t + ((size_t)(b * P_ + n0 + wn + i * 16 + l15)) * C_ + qd * 8;
    }

    f32x4 zero = {0.f, 0.f, 0.f, 0.f};
    f32x4 acc[4][4];
    #pragma unroll
    for (int mi = 0; mi < 4; ++mi)
        #pragma unroll
        for (int ni = 0; ni < 4; ++ni)
            acc[mi][ni] = zero;

    // flat barrier-free K-loop: 8 segments x (8 loads + 16 MFMA)
    #pragma unroll
    for (int seg = 0; seg < 8; ++seg) {
        const int ko = seg * 32;             // k-offset in elements
        bf16x8 af[4], bfr[4];
        #pragma unroll
        for (int i = 0; i < 4; ++i) {
            af[i]  = *(const bf16x8*)(aB[i] + ko);
            bfr[i] = *(const bf16x8*)(bB[i] + ko);
        }
        #pragma unroll
        for (int mi = 0; mi < 4; ++mi)
            #pragma unroll
            for (int ni = 0; ni < 4; ++ni)
                acc[mi][ni] = __builtin_amdgcn_mfma_f32_16x16x32_bf16(
                    af[mi], bfr[ni], acc[mi][ni], 0, 0, 0);
    }

    // ---- epilogue: acc -> LDS bf16 tile (scaled) ----
    const float sc = 0.0625f;   // 1/sqrt(256)
    __hip_bfloat16* tile = (__hip_bfloat16*)smem;
    #pragma unroll
    for (int mi = 0; mi < 4; ++mi) {
        #pragma unroll
        for (int ni = 0; ni < 4; ++ni) {
            #pragma unroll
            for (int r = 0; r < 4; ++r) {
                const int rl = wm + mi * 16 + qd * 4 + r;
                const int cl = wn + ni * 16 + l15;
                tile[rl * TSTR + cl] = __float2bfloat16(acc[mi][ni][r] * sc);
            }
        }
    }
    __syncthreads();

    // corr0: 2048 16B chunks, 8 per thread
    #pragma unroll
    for (int i = 0; i < 8; ++i) {
        const int cid = i * 256 + tid;
        const int tr  = cid >> 4;
        const int tc  = cid & 15;
        const float4 v = *(const float4*)(smem + tr * TSTR + tc * 8);
        *(float4*)(corr0 + ((size_t)(b * P_ + m0 + tr)) * P_ + n0 + tc * 8) = v;
    }

    // fused pool1 -> corr1: each thread pools TWO adjacent columns and
    // stores one packed u32 (2 bf16). 8 iters x 256 threads = 128x16 pairs.
    #pragma unroll
    for (int i = 0; i < 8; ++i) {
        const int oid = i * 256 + tid;
        const int pr  = oid >> 4;       // row 0..127
        const int j   = oid & 15;       // column-pair 0..15
        const uint32_t* r0 = (const uint32_t*)(smem + pr * TSTR + 4 * j);
        const uint32_t* r1 = (const uint32_t*)(smem + pr * TSTR + 64 + 4 * j);
        const uint32_t a01 = r0[0], a23 = r0[1];
        const uint32_t b01 = r1[0], b23 = r1[1];
        const float v0 = (__uint_as_float(a01 << 16) +
                          __uint_as_float(a01 & 0xffff0000u) +
                          __uint_as_float(b01 << 16) +
                          __uint_as_float(b01 & 0xffff0000u)) * 0.25f;
        const float v1 = (__uint_as_float(a23 << 16) +
                          __uint_as_float(a23 & 0xffff0000u) +
                          __uint_as_float(b23 << 16) +
                          __uint_as_float(b23 & 0xffff0000u)) * 0.25f;
        union { __hip_bfloat16 h[2]; uint32_t u; } pk;
        pk.h[0] = __float2bfloat16(v0);
        pk.h[1] = __float2bfloat16(v1);
        *(uint32_t*)(corr1 + ((size_t)(b * P_ + m0 + pr)) * 1024 +
                     bx * 32 + 2 * j) = pk.u;
    }
}

// ---------------------------------------------------------------------------
// Gather v5 (unchanged, validated): one block per (b,p), wave per n.
// ---------------------------------------------------------------------------
__global__ __launch_bounds__(256) void gather5(
    const float* __restrict__ coords,
    const __hip_bfloat16* __restrict__ c0,
    const __hip_bfloat16* __restrict__ c1,
    float* __restrict__ out) {
    __shared__ float pool_sm[320];     // [0..255]=c2 (16x16), [256..319]=c3 (8x8)
    __shared__ float patch[4][440];    // per wave: 4 levels x 110

    const int tid  = threadIdx.x;
    const int lane = tid & 63;
    const int n    = tid >> 6;
    const int bp   = blockIdx.x;       // 0..8191
    const int b    = bp >> 12;
    const int p    = bp & (P_ - 1);

    const __hip_bfloat16* c0b = c0 + (size_t)bp * 4096;
    const __hip_bfloat16* c1b = c1 + (size_t)bp * 1024;

    // ---- geometry, all 4 levels, all lanes ----
    const float cx = coords[((size_t)((b * N_ + n) * 2 + 0)) * P_ + p];
    const float cy = coords[((size_t)((b * N_ + n) * 2 + 1)) * P_ + p];
    int x0i[4], y0i[4];
    float w00[4], w01[4], w10[4], w11[4];
    #pragma unroll
    for (int l = 0; l < 4; ++l) {
        const float inv = (l == 0) ? 1.f : (l == 1) ? 0.5f : (l == 2) ? 0.25f : 0.125f;
        const float x = cx * inv, y = cy * inv;
        const float x0f = floorf(x), y0f = floorf(y);
        const float wx = x - x0f, wy = y - y0f;
        x0i[l] = (int)x0f - RAD;
        y0i[l] = (int)y0f - RAD;
        w00[l] = (1.f - wy) * (1.f - wx);
        w01[l] = (1.f - wy) * wx;
        w10[l] = wy * (1.f - wx);
        w11[l] = wy * wx;
    }

    // ---- prefetch level-0/1 patch values into registers ----
    float pv[2][2];
    #pragma unroll
    for (int lvl = 0; lvl < 2; ++lvl) {
        const __hip_bfloat16* src = lvl ? c1b : c0b;
        const int hw = lvl ? 32 : 64;
        const int sh = lvl ? 5 : 6;
        #pragma unroll
        for (int it = 0; it < 2; ++it) {
            const int idx = it * 64 + lane;
            const int r   = idx / 11;
            const int cc  = idx - r * 11;
            const int gr  = y0i[lvl] + r, gc = x0i[lvl] + cc;
            float v = 0.f;
            if ((idx < 110) & (cc < 10) & ((unsigned)gr < (unsigned)hw) &
                ((unsigned)gc < (unsigned)hw))
                v = __bfloat162float(src[(gr << sh) + gc]);
            pv[lvl][it] = v;
        }
    }

    // ---- Phase A: pool c1 -> c2, c3 (LDS); overlaps prefetch latency ----
    {
        const int y2 = tid >> 4, x2 = tid & 15;
        const uint32_t u0 = *(const uint32_t*)(c1b + (2 * y2) * 32 + 2 * x2);
        const uint32_t u1 = *(const uint32_t*)(c1b + (2 * y2 + 1) * 32 + 2 * x2);
        const float a0 = __uint_as_float(u0 << 16);
        const float a1 = __uint_as_float(u0 & 0xffff0000u);
        const float b0 = __uint_as_float(u1 << 16);
        const float b1 = __uint_as_float(u1 & 0xffff0000u);
        pool_sm[tid] = (a0 + a1 + b0 + b1) * 0.25f;
    }
    __syncthreads();
    if (tid < 64) {
        const int y3 = tid >> 3, x3 = tid & 7;
        const float* r0 = pool_sm + (2 * y3) * 16 + 2 * x3;
        pool_sm[256 + tid] = (r0[0] + r0[1] + r0[16] + r0[17]) * 0.25f;
    }
    __syncthreads();

    // ---- patch fill: lvl0/1 from regs, lvl2/3 from pool_sm ----
    float* pw = patch[n];
    #pragma unroll
    for (int lvl = 0; lvl < 2; ++lvl) {
        #pragma unroll
        for (int it = 0; it < 2; ++it) {
            const int idx = it * 64 + lane;
            if (idx < 110) pw[lvl * 110 + idx] = pv[lvl][it];
        }
    }
    #pragma unroll
    for (int lvl = 2; lvl < 4; ++lvl) {
        const int hw   = (lvl == 2) ? 16 : 8;
        const int sh   = (lvl == 2) ? 4 : 3;
        const int base = (lvl == 2) ? 0 : 256;
        #pragma unroll
        for (int it = 0; it < 2; ++it) {
            const int idx = it * 64 + lane;
            if (idx < 110) {
                const int r  = idx / 11;
                const int cc = idx - r * 11;
                const int gr = y0i[lvl] + r, gc = x0i[lvl] + cc;
                float v = 0.f;
                if ((cc < 10) & ((unsigned)gr < (unsigned)hw) &
                    ((unsigned)gc < (unsigned)hw))
                    v = pool_sm[base + (gr << sh) + gc];
                pw[lvl * 110 + idx] = v;
            }
        }
    }
    // no barrier: patch[n] is wave-private, wave LDS ops are in-order

    // ---- Phase C: per-level unrolled, 81 outputs each ----
    const size_t obase = ((size_t)(b * N_ + n) * P_ + p) * CTOT;
    #pragma unroll
    for (int lvl = 0; lvl < 4; ++lvl) {
        const float* pl = pw + lvl * 110;
        float* ol = out + obase + lvl * K2_;
        #pragma unroll
        for (int it = 0; it < 2; ++it) {
            const int k2 = it * 64 + lane;
            if (k2 < K2_) {
                const int ki = k2 / 9;        // added to x -> patch col
                const int kj = k2 - ki * 9;   // added to y -> patch row
                const float* pr = pl + kj * 11 + ki;
                ol[k2] = w00[lvl] * pr[0] + w01[lvl] * pr[1] +
                         w10[lvl] * pr[11] + w11[lvl] * pr[12];
            }
        }
    }
}

// ---------------------------------------------------------------------------
extern "C" void kernel_launch(void* const* d_in, const int* in_sizes, int n_in,
                              void* d_out, int out_size, void* d_ws, size_t ws_size,
                              hipStream_t stream) {
    const float* fmap1  = (const float*)d_in[0];
    const float* fmap2  = (const float*)d_in[1];
    const float* coords = (const float*)d_in[2];
    float* out = (float*)d_out;

    char* ws = (char*)d_ws;
    __hip_bfloat16* f1t = (__hip_bfloat16*)ws;                    //  4,194,304 B
    __hip_bfloat16* f2t = (__hip_bfloat16*)(ws + 4194304);        //  4,194,304 B
    __hip_bfloat16* c0  = (__hip_bfloat16*)(ws + 8388608);        // 67,108,864 B
    __hip_bfloat16* c1  = (__hip_bfloat16*)(ws + 75497472);       // 16,777,216 B

    // 1) transpose+convert both fmaps (one dispatch)
    {
        dim3 grid(P_ / 32, C_ / 32, 2 * B_);
        dim3 blk(32, 8);
        transpose_cvt<<<grid, blk, 0, stream>>>(fmap1, fmap2, f1t, f2t);
    }

    // 2) all-pairs correlation (level 0) + fused level-1 pooling
    {
        dim3 grid(P_ / 128, P_ / 128, B_);
        gemm_corr<<<grid, 256, 0, stream>>>((const short*)f1t, (const short*)f2t,
                                            c0, c1);
    }

    // 3) fused pool2+pool3 + 4-level bilinear gather
    gather5<<<B_ * P_, 256, 0, stream>>>(coords, c0, c1, out);
}